// Round 2
// baseline (524.111 us; speedup 1.0000x reference)
//
#include <hip/hip_runtime.h>

#define B_SZ 4
#define SEQ  2048
#define CH   768
#define NH   12
#define HD   64

typedef float f32x4  __attribute__((ext_vector_type(4)));
typedef float f32x16 __attribute__((ext_vector_type(16)));
typedef __bf16 bf16x8 __attribute__((ext_vector_type(8)));
typedef __bf16 bf16x2 __attribute__((ext_vector_type(2)));

#define MFMA16(a,b,c) __builtin_amdgcn_mfma_f32_16x16x32_bf16(a,b,c,0,0,0)
#define MFMA32(a,b,c) __builtin_amdgcn_mfma_f32_32x32x16_bf16(a,b,c,0,0,0)

// scale = 1/sqrt(64) * log2(e)  -> lets softmax use exp2
#define QSCALE 0.1803368801111204f

__device__ __forceinline__ unsigned pack2(float a, float b) {
    union { bf16x2 v; unsigned u; } p;
    p.v[0] = (__bf16)a; p.v[1] = (__bf16)b;
    return p.u;
}

// async global->LDS, 16B per lane. lds dest must be uniform + lane*16.
__device__ __forceinline__ void lds_dma16(const void* g, void* l) {
    __builtin_amdgcn_global_load_lds(
        (const __attribute__((address_space(1))) void*)g,
        (__attribute__((address_space(3))) void*)(unsigned)(unsigned long long)l,
        16, 0, 0);
}

// ---------------- fp32 -> bf16 convert ----------------
__global__ __launch_bounds__(256) void convert_bf16(const float* __restrict__ src,
                                                    __bf16* __restrict__ dst, int n) {
    int i = (blockIdx.x * 256 + threadIdx.x) * 4;
    if (i >= n) return;
    float4 v = *(const float4*)(src + i);
    union { __bf16 h[4]; uint2 u; } o;
    o.h[0] = (__bf16)v.x; o.h[1] = (__bf16)v.y; o.h[2] = (__bf16)v.z; o.h[3] = (__bf16)v.w;
    *(uint2*)(dst + i) = o.u;
}

// ---------------- 128x128 tile (BK=64) MFMA mainloop: C = A(MxK) * B(NxK)^T ----------------
// LDS layout: row-major [128][64] bf16, 16B chunk c stored at phys chunk c ^ (row&7)
// (conflict-free b128 reads; staging via global_load_lds width 16).
__device__ __forceinline__ void gemm128_loop(const __bf16* __restrict__ A,
                                             const __bf16* __restrict__ Bm,
                                             int K, int rowBlk, int colBlk,
                                             __bf16* As, __bf16* Bs,
                                             f32x4 acc[4][4]) {
    const int tid  = threadIdx.x;
    const int lane = tid & 63, wid = tid >> 6;
    const int quad = lane >> 4, l16 = lane & 15;
    const int wm = wid >> 1, wn = wid & 1;

    f32x4 z = {0.f, 0.f, 0.f, 0.f};
#pragma unroll
    for (int mi = 0; mi < 4; ++mi)
#pragma unroll
        for (int ni = 0; ni < 4; ++ni) acc[mi][ni] = z;

    for (int k0 = 0; k0 < K; k0 += 64) {
        __syncthreads();   // prior-iteration LDS readers done
#pragma unroll
        for (int i = 0; i < 4; ++i) {
            int s = i * 256 + tid;
            int row = s >> 3, pc = s & 7;
            int lc = pc ^ (row & 7);
            lds_dma16(A  + (size_t)(rowBlk + row) * K + k0 + lc * 8, As + s * 8);
            lds_dma16(Bm + (size_t)(colBlk + row) * K + k0 + lc * 8, Bs + s * 8);
        }
        __syncthreads();   // drains vmcnt (incl. lds-dma) per barrier semantics

#pragma unroll
        for (int kc = 0; kc < 2; ++kc) {
            bf16x8 af[4], bf[4];
#pragma unroll
            for (int mi = 0; mi < 4; ++mi) {
                int row = wm * 64 + mi * 16 + l16;
                int pc = (quad + 4 * kc) ^ (row & 7);
                af[mi] = *(const bf16x8*)(As + row * 64 + pc * 8);
            }
#pragma unroll
            for (int ni = 0; ni < 4; ++ni) {
                int row = wn * 64 + ni * 16 + l16;
                int pc = (quad + 4 * kc) ^ (row & 7);
                bf[ni] = *(const bf16x8*)(Bs + row * 64 + pc * 8);
            }
#pragma unroll
            for (int mi = 0; mi < 4; ++mi)
#pragma unroll
                for (int ni = 0; ni < 4; ++ni)
                    acc[mi][ni] = MFMA16(af[mi], bf[ni], acc[mi][ni]);
        }
    }
}

// ---------------- QKV GEMM: X(8192x768) @ Wqkv(2304x768)^T, scatter to Q/K/Vt ----------------
__global__ __launch_bounds__(256) void qkv_gemm(const __bf16* __restrict__ Xb,
                                                const __bf16* __restrict__ Wb,
                                                __bf16* __restrict__ Qb,
                                                __bf16* __restrict__ Kb,
                                                __bf16* __restrict__ Vt) {
    __shared__ __bf16 As[128 * 64];
    __shared__ __bf16 Bs[128 * 64];
    f32x4 acc[4][4];
    const int rowBlk = blockIdx.x * 128, colBlk = blockIdx.y * 128;
    gemm128_loop(Xb, Wb, CH, rowBlk, colBlk, As, Bs, acc);

    const int lane = threadIdx.x & 63, wid = threadIdx.x >> 6;
    const int quad = lane >> 4, l16 = lane & 15, wm = wid >> 1, wn = wid & 1;
#pragma unroll
    for (int mi = 0; mi < 4; ++mi)
#pragma unroll
        for (int ni = 0; ni < 4; ++ni)
#pragma unroll
            for (int r = 0; r < 4; ++r) {
                int row = rowBlk + wm * 64 + mi * 16 + quad * 4 + r;  // 0..8191
                int col = colBlk + wn * 64 + ni * 16 + l16;           // 0..2303
                float v = acc[mi][ni][r];
                int b = row >> 11, n = row & (SEQ - 1);
                int which = (col >= 2 * CH) ? 2 : ((col >= CH) ? 1 : 0);
                int cc = col - which * CH;
                int h = cc >> 6, d = cc & 63;
                int bh = b * NH + h;
                if (which == 0)      Qb[(size_t)(bh * SEQ + n) * HD + d] = (__bf16)(v * QSCALE);
                else if (which == 1) Kb[(size_t)(bh * SEQ + n) * HD + d] = (__bf16)v;
                else                 Vt[(size_t)(bh * HD + d) * SEQ + n] = (__bf16)v;
            }
}

// ---------------- Flash attention v2: S^T = K Q^T (32x32 MFMA), fixed-max softmax ----------------
// Block: 4 waves x 32 queries = 128 queries. Only V^T staged in LDS; K read from global (L2).
__global__ __launch_bounds__(256, 3) void flash_attn(const __bf16* __restrict__ Qb,
                                                     const __bf16* __restrict__ Kb,
                                                     const __bf16* __restrict__ Vt,
                                                     __bf16* __restrict__ Ab) {
    __shared__ __bf16 Buf[128][72];   // rows 0..63: V^T tile [d][key]; all 128 rows for epilogue

    const int tid  = threadIdx.x;
    const int lane = tid & 63, wid = tid >> 6;
    const int l32  = lane & 31, half = lane >> 5;

    const int qblk = blockIdx.x;       // 0..15 (128 queries each)
    const int head = blockIdx.y;       // 0..11
    const int b    = blockIdx.z;       // 0..3
    const int bh   = b * NH + head;

    const int q = qblk * 128 + wid * 32 + l32;

    // Q^T B-fragments: lane holds col q, k-dim = kc*16 + half*8 + j  (held whole kernel)
    bf16x8 qf[4];
#pragma unroll
    for (int kc = 0; kc < 4; ++kc)
        qf[kc] = *(const bf16x8*)(Qb + (size_t)(bh * SEQ + q) * HD + kc * 16 + half * 8);

    f32x16 ot[2];
#pragma unroll
    for (int nd = 0; nd < 2; ++nd)
#pragma unroll
        for (int r = 0; r < 16; ++r) ot[nd][r] = 0.f;
    float l_part = 0.f;

    for (int kb = 0; kb < SEQ / 64; ++kb) {
        const int kbase = kb * 64;
        __syncthreads();   // prior-iteration V readers done
        {   // stage V^T 64d x 64keys (8KB): thread t -> row t>>2, 2x16B
            int r  = tid >> 2;
            int c0 = (tid & 3) * 16;
            const __bf16* src = Vt + (size_t)(bh * HD + r) * SEQ + kbase + c0;
            *(uint4*)(&Buf[r][c0])     = *(const uint4*)(src);
            *(uint4*)(&Buf[r][c0 + 8]) = *(const uint4*)(src + 8);
        }
        __syncthreads();

        // S^T = K . Q^T : 2 key tiles x 4 k-chunks; K A-frags straight from global
        f32x16 st[2];
#pragma unroll
        for (int nb = 0; nb < 2; ++nb) {
#pragma unroll
            for (int r = 0; r < 16; ++r) st[nb][r] = 0.f;
#pragma unroll
            for (int kc = 0; kc < 4; ++kc) {
                bf16x8 kf = *(const bf16x8*)(Kb + (size_t)(bh * SEQ + kbase + nb * 32 + l32) * HD
                                             + kc * 16 + half * 8);
                st[nb] = MFMA32(kf, qf[kc], st[nb]);
            }
        }

        // p = 2^(s)  (Q pre-scaled by 0.125*log2e) ; all 32 values belong to query q=l32
#pragma unroll
        for (int t = 0; t < 2; ++t)
#pragma unroll
            for (int r = 0; r < 16; ++r) {
                float p = exp2f(st[t][r]);
                st[t][r] = p;
                l_part += p;
            }

        // P^T B-fragments: chunk g = t*2+c (16 keys). keep = own regs 8c+4h..+3,
        // recv = partner regs 8c+4(1-h)..+3 via shfl_xor(32).
        bf16x8 pf[4];
#pragma unroll
        for (int t = 0; t < 2; ++t)
#pragma unroll
            for (int c = 0; c < 2; ++c) {
                int kb_ = 8 * c + 4 * half;
                int sb_ = 8 * c + 4 * (1 - half);
                unsigned k0 = pack2(st[t][kb_ + 0], st[t][kb_ + 1]);
                unsigned k1 = pack2(st[t][kb_ + 2], st[t][kb_ + 3]);
                unsigned s0 = pack2(st[t][sb_ + 0], st[t][sb_ + 1]);
                unsigned s1 = pack2(st[t][sb_ + 2], st[t][sb_ + 3]);
                unsigned r0 = (unsigned)__shfl_xor((int)s0, 32, 64);
                unsigned r1 = (unsigned)__shfl_xor((int)s1, 32, 64);
                union { bf16x8 v; unsigned u[4]; } f;
                f.u[0] = half ? r0 : k0;
                f.u[1] = half ? r1 : k1;
                f.u[2] = half ? k0 : r0;
                f.u[3] = half ? k1 : r1;
                pf[t * 2 + c] = f.v;
            }

        // O^T += V^T . P^T
#pragma unroll
        for (int nd = 0; nd < 2; ++nd)
#pragma unroll
            for (int g = 0; g < 4; ++g) {
                bf16x8 vf = *(const bf16x8*)(&Buf[nd * 32 + l32][g * 16 + half * 8]);
                ot[nd] = MFMA32(vf, pf[g], ot[nd]);
            }
    }

    // finalize: l(q) = own half + partner half
    float l_full = l_part + __shfl_xor(l_part, 32, 64);
    float rinv = 1.f / l_full;

    __syncthreads();   // last PV reads done; reuse Buf for O transpose
#pragma unroll
    for (int nd = 0; nd < 2; ++nd)
#pragma unroll
        for (int r = 0; r < 16; ++r) {
            int d = nd * 32 + (r & 3) + 8 * (r >> 2) + 4 * half;
            Buf[wid * 32 + l32][d] = (__bf16)(ot[nd][r] * rinv);
        }
    __syncthreads();
#pragma unroll
    for (int p = 0; p < 4; ++p) {
        int ql = (lane >> 3) + p * 8;
        int c  = (lane & 7) * 8;
        uint4 v = *(const uint4*)(&Buf[wid * 32 + ql][c]);
        *(uint4*)(Ab + (size_t)(b * SEQ + qblk * 128 + wid * 32 + ql) * CH + head * HD + c) = v;
    }
}

// ---------------- Projection GEMM: Attn(8192x768) @ proj_w(768x768)^T + bias ----------------
__global__ __launch_bounds__(256) void proj_gemm(const __bf16* __restrict__ Ab,
                                                 const __bf16* __restrict__ Pw,
                                                 const float* __restrict__ bias,
                                                 float* __restrict__ out) {
    __shared__ __bf16 As[128 * 64];
    __shared__ __bf16 Bs[128 * 64];
    f32x4 acc[4][4];
    const int rowBlk = blockIdx.x * 128, colBlk = blockIdx.y * 128;
    gemm128_loop(Ab, Pw, CH, rowBlk, colBlk, As, Bs, acc);

    const int lane = threadIdx.x & 63, wid = threadIdx.x >> 6;
    const int quad = lane >> 4, l16 = lane & 15, wm = wid >> 1, wn = wid & 1;
#pragma unroll
    for (int mi = 0; mi < 4; ++mi)
#pragma unroll
        for (int ni = 0; ni < 4; ++ni)
#pragma unroll
            for (int r = 0; r < 4; ++r) {
                int row = rowBlk + wm * 64 + mi * 16 + quad * 4 + r;
                int col = colBlk + wn * 64 + ni * 16 + l16;
                out[(size_t)row * CH + col] = acc[mi][ni][r] + bias[col];
            }
}

extern "C" void kernel_launch(void* const* d_in, const int* in_sizes, int n_in,
                              void* d_out, int out_size, void* d_ws, size_t ws_size,
                              hipStream_t stream) {
    const float* x      = (const float*)d_in[0];   // (4,2048,768)
    const float* qkv_w  = (const float*)d_in[1];   // (2304,768)
    const float* proj_w = (const float*)d_in[2];   // (768,768)
    const float* proj_b = (const float*)d_in[3];   // (768,)
    float* out = (float*)d_out;

    char* ws = (char*)d_ws;
    const size_t nX = (size_t)B_SZ * SEQ * CH;        // 6,291,456
    const size_t nW = (size_t)3 * CH * CH;            // 1,769,472
    const size_t nP = (size_t)CH * CH;                // 589,824
    const size_t nQ = (size_t)B_SZ * NH * SEQ * HD;   // 6,291,456

    __bf16* Xb = (__bf16*)(ws);
    __bf16* Wb = (__bf16*)(ws + 2 * nX);
    __bf16* Pw = (__bf16*)(ws + 2 * (nX + nW));
    __bf16* Qb = (__bf16*)(ws + 2 * (nX + nW + nP));
    __bf16* Kb = (__bf16*)(ws + 2 * (nX + nW + nP + nQ));
    __bf16* Vt = (__bf16*)(ws + 2 * (nX + nW + nP + 2 * nQ));
    __bf16* Ab = (__bf16*)(ws + 2 * (nX + nW + nP + 3 * nQ));

    convert_bf16<<<(int)(nX / 1024), 256, 0, stream>>>(x, Xb, (int)nX);
    convert_bf16<<<(int)(nW / 1024), 256, 0, stream>>>(qkv_w, Wb, (int)nW);
    convert_bf16<<<(int)(nP / 1024), 256, 0, stream>>>(proj_w, Pw, (int)nP);

    qkv_gemm<<<dim3((B_SZ * SEQ) / 128, (3 * CH) / 128), 256, 0, stream>>>(Xb, Wb, Qb, Kb, Vt);

    flash_attn<<<dim3(SEQ / 128, NH, B_SZ), 256, 0, stream>>>(Qb, Kb, Vt, Ab);

    proj_gemm<<<dim3((B_SZ * SEQ) / 128, CH / 128), 256, 0, stream>>>(Ab, Pw, proj_b, out);
}

// Round 3
// 454.631 us; speedup vs baseline: 1.1528x; 1.1528x over previous
//
#include <hip/hip_runtime.h>

#define B_SZ 4
#define SEQ  2048
#define CH   768
#define NH   12
#define HD   64

typedef float f32x4  __attribute__((ext_vector_type(4)));
typedef float f32x16 __attribute__((ext_vector_type(16)));
typedef __bf16 bf16x8 __attribute__((ext_vector_type(8)));
typedef __bf16 bf16x2 __attribute__((ext_vector_type(2)));

#define MFMA16(a,b,c) __builtin_amdgcn_mfma_f32_16x16x32_bf16(a,b,c,0,0,0)
#define MFMA32(a,b,c) __builtin_amdgcn_mfma_f32_32x32x16_bf16(a,b,c,0,0,0)

// scale = 1/sqrt(64) * log2(e)  -> softmax uses raw exp2
#define QSCALE 0.1803368801111204f

#if __has_builtin(__builtin_amdgcn_exp2f)
#define EXP2(x) __builtin_amdgcn_exp2f(x)
#else
#define EXP2(x) exp2f(x)
#endif

__device__ __forceinline__ unsigned pack2(float a, float b) {
    union { bf16x2 v; unsigned u; } p;
    p.v[0] = (__bf16)a; p.v[1] = (__bf16)b;
    return p.u;
}

// async global->LDS, 16B per lane. lds dest must be uniform + lane*16.
__device__ __forceinline__ void lds_dma16(const void* g, void* l) {
    __builtin_amdgcn_global_load_lds(
        (const __attribute__((address_space(1))) void*)g,
        (__attribute__((address_space(3))) void*)(unsigned)(unsigned long long)l,
        16, 0, 0);
}

// ---------------- fp32 -> bf16 convert ----------------
__global__ __launch_bounds__(256) void convert_bf16(const float* __restrict__ src,
                                                    __bf16* __restrict__ dst, int n) {
    int i = (blockIdx.x * 256 + threadIdx.x) * 4;
    if (i >= n) return;
    float4 v = *(const float4*)(src + i);
    union { __bf16 h[4]; uint2 u; } o;
    o.h[0] = (__bf16)v.x; o.h[1] = (__bf16)v.y; o.h[2] = (__bf16)v.z; o.h[3] = (__bf16)v.w;
    *(uint2*)(dst + i) = o.u;
}

// ---------------- 128x128 tile (BK=64) MFMA mainloop: C = A(MxK) * B(NxK)^T ----------------
// LDS layout: row-major [128][64] bf16, 16B chunk c stored at phys chunk c ^ (row&7).
__device__ __forceinline__ void gemm128_loop(const __bf16* __restrict__ A,
                                             const __bf16* __restrict__ Bm,
                                             int K, int rowBlk, int colBlk,
                                             __bf16* As, __bf16* Bs,
                                             f32x4 acc[4][4]) {
    const int tid  = threadIdx.x;
    const int lane = tid & 63, wid = tid >> 6;
    const int quad = lane >> 4, l16 = lane & 15;
    const int wm = wid >> 1, wn = wid & 1;

    f32x4 z = {0.f, 0.f, 0.f, 0.f};
#pragma unroll
    for (int mi = 0; mi < 4; ++mi)
#pragma unroll
        for (int ni = 0; ni < 4; ++ni) acc[mi][ni] = z;

    for (int k0 = 0; k0 < K; k0 += 64) {
        __syncthreads();
#pragma unroll
        for (int i = 0; i < 4; ++i) {
            int s = i * 256 + tid;
            int row = s >> 3, pc = s & 7;
            int lc = pc ^ (row & 7);
            lds_dma16(A  + (size_t)(rowBlk + row) * K + k0 + lc * 8, As + s * 8);
            lds_dma16(Bm + (size_t)(colBlk + row) * K + k0 + lc * 8, Bs + s * 8);
        }
        __syncthreads();

#pragma unroll
        for (int kc = 0; kc < 2; ++kc) {
            bf16x8 af[4], bfr[4];
#pragma unroll
            for (int mi = 0; mi < 4; ++mi) {
                int row = wm * 64 + mi * 16 + l16;
                int pc = (quad + 4 * kc) ^ (row & 7);
                af[mi] = *(const bf16x8*)(As + row * 64 + pc * 8);
            }
#pragma unroll
            for (int ni = 0; ni < 4; ++ni) {
                int row = wn * 64 + ni * 16 + l16;
                int pc = (quad + 4 * kc) ^ (row & 7);
                bfr[ni] = *(const bf16x8*)(Bs + row * 64 + pc * 8);
            }
#pragma unroll
            for (int mi = 0; mi < 4; ++mi)
#pragma unroll
                for (int ni = 0; ni < 4; ++ni)
                    acc[mi][ni] = MFMA16(af[mi], bfr[ni], acc[mi][ni]);
        }
    }
}

// ---------------- QKV GEMM: X(8192x768) @ Wqkv(2304x768)^T, scatter to Q/K/Vt ----------------
// col blocks 0..5 -> Q, 6..11 -> K, 12..17 -> V (boundaries are multiples of 128).
__global__ __launch_bounds__(256) void qkv_gemm(const __bf16* __restrict__ Xb,
                                                const __bf16* __restrict__ Wb,
                                                __bf16* __restrict__ Qb,
                                                __bf16* __restrict__ Kb,
                                                __bf16* __restrict__ Vt) {
    __shared__ __bf16 smem[128 * 128];   // 32 KB: mainloop uses first 16 KB; V-epilogue all
    f32x4 acc[4][4];
    const int rowBlk = blockIdx.x * 128, colBlk = blockIdx.y * 128;
    gemm128_loop(Xb, Wb, CH, rowBlk, colBlk, smem, smem + 128 * 64, acc);

    const int tid = threadIdx.x;
    const int lane = tid & 63, wid = tid >> 6;
    const int quad = lane >> 4, l16 = lane & 15, wm = wid >> 1, wn = wid & 1;
    const int b = rowBlk >> 11, n0 = rowBlk & (SEQ - 1);

    if (colBlk < 2 * CH) {
        // Q or K: direct store
        const int isK = (colBlk >= CH);
#pragma unroll
        for (int mi = 0; mi < 4; ++mi)
#pragma unroll
            for (int ni = 0; ni < 4; ++ni)
#pragma unroll
                for (int r = 0; r < 4; ++r) {
                    int n = n0 + wm * 64 + mi * 16 + quad * 4 + r;
                    int cc = colBlk - (isK ? CH : 0) + wn * 64 + ni * 16 + l16;
                    int h = cc >> 6, d = cc & 63;
                    size_t idx = (size_t)((b * NH + h) * SEQ + n) * HD + d;
                    float v = acc[mi][ni][r];
                    if (isK) Kb[idx] = (__bf16)v;
                    else     Qb[idx] = (__bf16)(v * QSCALE);
                }
    } else {
        // V: transpose through LDS, write V^T coalesced (16B chunks along n)
        const int vblk = colBlk - 2 * CH;    // 0..640, step 128
        __syncthreads();   // mainloop LDS reads done
#pragma unroll
        for (int mi = 0; mi < 4; ++mi)
#pragma unroll
            for (int ni = 0; ni < 4; ++ni)
#pragma unroll
                for (int r = 0; r < 4; ++r) {
                    int rl = wm * 64 + mi * 16 + quad * 4 + r;   // n-local
                    int cl = wn * 64 + ni * 16 + l16;            // d-local
                    smem[cl * 128 + (((rl >> 3) ^ (cl & 15)) << 3) + (rl & 7)] =
                        (__bf16)acc[mi][ni][r];
                }
        __syncthreads();
        const int dl = tid >> 1;                 // d-local row 0..127
        const int d  = vblk + dl;
        const int h  = d >> 6, dd = d & 63;
        const size_t base = (size_t)((b * NH + h) * HD + dd) * SEQ + n0;
#pragma unroll
        for (int j2 = 0; j2 < 8; ++j2) {
            int j = (tid & 1) * 8 + j2;          // 16B chunk along n
            uint4 val = *(const uint4*)(smem + dl * 128 + ((j ^ (dl & 15)) << 3));
            *(uint4*)(Vt + base + j * 8) = val;
        }
    }
}

// ---------------- Flash attention v3: S^T = K Q^T, K via lds_dma16+swizzle, V^T padded ----------------
__global__ __launch_bounds__(256, 3) void flash_attn(const __bf16* __restrict__ Qb,
                                                     const __bf16* __restrict__ Kb,
                                                     const __bf16* __restrict__ Vt,
                                                     __bf16* __restrict__ Ab) {
    __shared__ __bf16 smem[128 * 72];            // 18 KB
    __bf16* Ks = smem;                           // 64x64 swizzled (8 KB)
    __bf16 (*Vs)[72] = (__bf16(*)[72])(smem + 64 * 64);  // 64x72 padded (9 KB)

    const int tid  = threadIdx.x;
    const int lane = tid & 63, wid = tid >> 6;
    const int l32  = lane & 31, half = lane >> 5;

    const int qblk = blockIdx.x;       // 0..15 (128 queries each)
    const int head = blockIdx.y;
    const int b    = blockIdx.z;
    const int bh   = b * NH + head;

    const int q = qblk * 128 + wid * 32 + l32;

    // Q^T B-fragments (held whole kernel): lane = col q, k-dim = kc*16 + half*8 + j
    bf16x8 qf[4];
#pragma unroll
    for (int kc = 0; kc < 4; ++kc)
        qf[kc] = *(const bf16x8*)(Qb + (size_t)(bh * SEQ + q) * HD + kc * 16 + half * 8);

    f32x16 ot[2];
#pragma unroll
    for (int nd = 0; nd < 2; ++nd)
#pragma unroll
        for (int r = 0; r < 16; ++r) ot[nd][r] = 0.f;
    float l_part = 0.f;

    const int vr = tid >> 2, vc = (tid & 3) * 16;
    const __bf16* vbase = Vt + (size_t)(bh * HD + vr) * SEQ + vc;

    for (int kb = 0; kb < SEQ / 64; ++kb) {
        const int kbase = kb * 64;
        __syncthreads();   // prior-iteration LDS readers done
        // V^T tile: manual uint4 (padded rows ok)
        uint4 v0 = *(const uint4*)(vbase + kbase);
        uint4 v1 = *(const uint4*)(vbase + kbase + 8);
        // K tile: async DMA, XOR-swizzled chunks
#pragma unroll
        for (int i = 0; i < 2; ++i) {
            int s = i * 256 + tid;
            int row = s >> 3, pc = s & 7;
            int lc = pc ^ (row & 7);
            lds_dma16(Kb + (size_t)(bh * SEQ + kbase + row) * HD + lc * 8, Ks + s * 8);
        }
        *(uint4*)(&Vs[vr][vc])     = v0;
        *(uint4*)(&Vs[vr][vc + 8]) = v1;
        __syncthreads();   // drains dma + lds stores

        // S^T = K . Q^T : K A-frags from swizzled LDS
        f32x16 st[2];
#pragma unroll
        for (int nb = 0; nb < 2; ++nb) {
#pragma unroll
            for (int r = 0; r < 16; ++r) st[nb][r] = 0.f;
#pragma unroll
            for (int kc = 0; kc < 4; ++kc) {
                int row = nb * 32 + l32;
                int c = kc * 2 + half;
                bf16x8 kf = *(const bf16x8*)(Ks + row * 64 + ((c ^ (row & 7)) << 3));
                st[nb] = MFMA32(kf, qf[kc], st[nb]);
            }
        }

        // p = 2^s (Q pre-scaled); all 32 values belong to query q = l32
#pragma unroll
        for (int t = 0; t < 2; ++t)
#pragma unroll
            for (int r = 0; r < 16; ++r) {
                float p = EXP2(st[t][r]);
                st[t][r] = p;
                l_part += p;
            }

        // P^T B-fragments via register exchange (shfl_xor 32)
        bf16x8 pf[4];
#pragma unroll
        for (int t = 0; t < 2; ++t)
#pragma unroll
            for (int c = 0; c < 2; ++c) {
                int kb_ = 8 * c + 4 * half;
                int sb_ = 8 * c + 4 * (1 - half);
                unsigned k0 = pack2(st[t][kb_ + 0], st[t][kb_ + 1]);
                unsigned k1 = pack2(st[t][kb_ + 2], st[t][kb_ + 3]);
                unsigned s0 = pack2(st[t][sb_ + 0], st[t][sb_ + 1]);
                unsigned s1 = pack2(st[t][sb_ + 2], st[t][sb_ + 3]);
                unsigned r0 = (unsigned)__shfl_xor((int)s0, 32, 64);
                unsigned r1 = (unsigned)__shfl_xor((int)s1, 32, 64);
                union { bf16x8 v; unsigned u[4]; } f;
                f.u[0] = half ? r0 : k0;
                f.u[1] = half ? r1 : k1;
                f.u[2] = half ? k0 : r0;
                f.u[3] = half ? k1 : r1;
                pf[t * 2 + c] = f.v;
            }

        // O^T += V^T . P^T
#pragma unroll
        for (int nd = 0; nd < 2; ++nd)
#pragma unroll
            for (int g = 0; g < 4; ++g) {
                bf16x8 vf = *(const bf16x8*)(&Vs[nd * 32 + l32][g * 16 + half * 8]);
                ot[nd] = MFMA32(vf, pf[g], ot[nd]);
            }
    }

    float l_full = l_part + __shfl_xor(l_part, 32, 64);
    float rinv = 1.f / l_full;

    __syncthreads();   // reuse smem as [128][72] for O transpose
    __bf16 (*Ob)[72] = (__bf16(*)[72])smem;
#pragma unroll
    for (int nd = 0; nd < 2; ++nd)
#pragma unroll
        for (int r = 0; r < 16; ++r) {
            int d = nd * 32 + (r & 3) + 8 * (r >> 2) + 4 * half;
            Ob[wid * 32 + l32][d] = (__bf16)(ot[nd][r] * rinv);
        }
    __syncthreads();
#pragma unroll
    for (int p = 0; p < 4; ++p) {
        int ql = (lane >> 3) + p * 8;
        int c  = (lane & 7) * 8;
        uint4 v = *(const uint4*)(&Ob[wid * 32 + ql][c]);
        *(uint4*)(Ab + (size_t)(b * SEQ + qblk * 128 + wid * 32 + ql) * CH + head * HD + c) = v;
    }
}

// ---------------- Projection GEMM: Attn(8192x768) @ proj_w(768x768)^T + bias ----------------
__global__ __launch_bounds__(256) void proj_gemm(const __bf16* __restrict__ Ab,
                                                 const __bf16* __restrict__ Pw,
                                                 const float* __restrict__ bias,
                                                 float* __restrict__ out) {
    __shared__ __bf16 As[128 * 64];
    __shared__ __bf16 Bs[128 * 64];
    f32x4 acc[4][4];
    const int rowBlk = blockIdx.x * 128, colBlk = blockIdx.y * 128;
    gemm128_loop(Ab, Pw, CH, rowBlk, colBlk, As, Bs, acc);

    const int lane = threadIdx.x & 63, wid = threadIdx.x >> 6;
    const int quad = lane >> 4, l16 = lane & 15, wm = wid >> 1, wn = wid & 1;
#pragma unroll
    for (int mi = 0; mi < 4; ++mi)
#pragma unroll
        for (int ni = 0; ni < 4; ++ni)
#pragma unroll
            for (int r = 0; r < 4; ++r) {
                int row = rowBlk + wm * 64 + mi * 16 + quad * 4 + r;
                int col = colBlk + wn * 64 + ni * 16 + l16;
                out[(size_t)row * CH + col] = acc[mi][ni][r] + bias[col];
            }
}

extern "C" void kernel_launch(void* const* d_in, const int* in_sizes, int n_in,
                              void* d_out, int out_size, void* d_ws, size_t ws_size,
                              hipStream_t stream) {
    const float* x      = (const float*)d_in[0];
    const float* qkv_w  = (const float*)d_in[1];
    const float* proj_w = (const float*)d_in[2];
    const float* proj_b = (const float*)d_in[3];
    float* out = (float*)d_out;

    char* ws = (char*)d_ws;
    const size_t nX = (size_t)B_SZ * SEQ * CH;
    const size_t nW = (size_t)3 * CH * CH;
    const size_t nP = (size_t)CH * CH;
    const size_t nQ = (size_t)B_SZ * NH * SEQ * HD;

    __bf16* Xb = (__bf16*)(ws);
    __bf16* Wb = (__bf16*)(ws + 2 * nX);
    __bf16* Pw = (__bf16*)(ws + 2 * (nX + nW));
    __bf16* Qb = (__bf16*)(ws + 2 * (nX + nW + nP));
    __bf16* Kb = (__bf16*)(ws + 2 * (nX + nW + nP + nQ));
    __bf16* Vt = (__bf16*)(ws + 2 * (nX + nW + nP + 2 * nQ));
    __bf16* Ab = (__bf16*)(ws + 2 * (nX + nW + nP + 3 * nQ));

    convert_bf16<<<(int)(nX / 1024), 256, 0, stream>>>(x, Xb, (int)nX);
    convert_bf16<<<(int)(nW / 1024), 256, 0, stream>>>(qkv_w, Wb, (int)nW);
    convert_bf16<<<(int)(nP / 1024), 256, 0, stream>>>(proj_w, Pw, (int)nP);

    qkv_gemm<<<dim3((B_SZ * SEQ) / 128, (3 * CH) / 128), 256, 0, stream>>>(Xb, Wb, Qb, Kb, Vt);

    flash_attn<<<dim3(SEQ / 128, NH, B_SZ), 256, 0, stream>>>(Qb, Kb, Vt, Ab);

    proj_gemm<<<dim3((B_SZ * SEQ) / 128, CH / 128), 256, 0, stream>>>(Ab, Pw, proj_b, out);
}